// Round 1
// baseline (3117.453 us; speedup 1.0000x reference)
//
#include <hip/hip_runtime.h>

// GCN 2-layer, collapsed:
//   layer1 is rank-1 (x is [N,1]) -> scalar aggregation s[c]
//   layer2 aggregates a 2-vector gp[r] = (relu(W1*a1+b1) @ W2) * dis[r]
// ws layout (floats): [0,N) deg->dis (overwritten in place)
//                     [N,2N) p  = x*dis (scatter payload, layer 1)
//                     [2N,3N) s = scalar accumulator (init = self-loop term)
//                     [3N,5N) gp = 2-vec scatter payload, layer 2
// d_out doubles as the layer-2 accumulator (init = self-loop term).

#define EDGE_BLOCKS 4096
#define TPB 256

__global__ void k_init_deg(float* __restrict__ deg, int n) {
    int i = blockIdx.x * blockDim.x + threadIdx.x;
    if (i < n) deg[i] = 1.0f;  // self-loop
}

__global__ void k_deg(const int* __restrict__ col, float* __restrict__ deg, int ne) {
    int tid = blockIdx.x * blockDim.x + threadIdx.x;
    int stride = gridDim.x * blockDim.x;
    int ne4 = ne >> 2;
    const int4* col4 = (const int4*)col;
    for (int e = tid; e < ne4; e += stride) {
        int4 c = col4[e];
        atomicAdd(&deg[c.x], 1.0f);
        atomicAdd(&deg[c.y], 1.0f);
        atomicAdd(&deg[c.z], 1.0f);
        atomicAdd(&deg[c.w], 1.0f);
    }
    // tail
    for (int e = (ne4 << 2) + tid; e < ne; e += stride)
        atomicAdd(&deg[col[e]], 1.0f);
}

// dis = 1/sqrt(deg) (deg >= 1 always, self-loops); p = x*dis; s init = p (self-loop term)
__global__ void k_dis(const float* __restrict__ x, float* __restrict__ deg_dis,
                      float* __restrict__ p, float* __restrict__ s, int n) {
    int i = blockIdx.x * blockDim.x + threadIdx.x;
    if (i >= n) return;
    float d = deg_dis[i];
    float dis = 1.0f / sqrtf(d);
    deg_dis[i] = dis;
    float pv = x[i] * dis;
    p[i] = pv;
    s[i] = pv;
}

__global__ void k_scatter1(const int* __restrict__ row, const int* __restrict__ col,
                           const float* __restrict__ p, float* __restrict__ s, int ne) {
    int tid = blockIdx.x * blockDim.x + threadIdx.x;
    int stride = gridDim.x * blockDim.x;
    int ne4 = ne >> 2;
    const int4* row4 = (const int4*)row;
    const int4* col4 = (const int4*)col;
    for (int e = tid; e < ne4; e += stride) {
        int4 r = row4[e];
        int4 c = col4[e];
        atomicAdd(&s[c.x], p[r.x]);
        atomicAdd(&s[c.y], p[r.y]);
        atomicAdd(&s[c.z], p[r.z]);
        atomicAdd(&s[c.w], p[r.w]);
    }
    for (int e = (ne4 << 2) + tid; e < ne; e += stride)
        atomicAdd(&s[col[e]], p[row[e]]);
}

// per-node MLP: a1 = dis*s; h1[k]=relu(W1[k]*a1+b1[k]); g = h1 @ W2; gp = g*dis
// out init = gp (self-loop term of layer 2)
__global__ void k_node(const float* __restrict__ dis, const float* __restrict__ s,
                       const float* __restrict__ W1, const float* __restrict__ b1,
                       const float* __restrict__ W2, const float* __restrict__ b2,
                       float* __restrict__ gp, float* __restrict__ out, int n) {
    int i = blockIdx.x * blockDim.x + threadIdx.x;
    if (i >= n) return;
    float d = dis[i];
    float a = d * s[i];
    float g0 = 0.0f, g1 = 0.0f;
#pragma unroll
    for (int k = 0; k < 16; ++k) {
        float h = fmaxf(W1[k] * a + b1[k], 0.0f);
        g0 += h * W2[2 * k];
        g1 += h * W2[2 * k + 1];
    }
    float gp0 = g0 * d, gp1 = g1 * d;
    float2* gp2 = (float2*)gp;
    gp2[i] = make_float2(gp0, gp1);
    float2* out2 = (float2*)out;
    out2[i] = make_float2(gp0, gp1);
}

__global__ void k_scatter2(const int* __restrict__ row, const int* __restrict__ col,
                           const float* __restrict__ gp, float* __restrict__ out, int ne) {
    int tid = blockIdx.x * blockDim.x + threadIdx.x;
    int stride = gridDim.x * blockDim.x;
    int ne4 = ne >> 2;
    const int4* row4 = (const int4*)row;
    const int4* col4 = (const int4*)col;
    const float2* gp2 = (const float2*)gp;
    for (int e = tid; e < ne4; e += stride) {
        int4 r = row4[e];
        int4 c = col4[e];
        float2 ga = gp2[r.x];
        float2 gb = gp2[r.y];
        float2 gc = gp2[r.z];
        float2 gd = gp2[r.w];
        atomicAdd(&out[2 * c.x], ga.x);
        atomicAdd(&out[2 * c.x + 1], ga.y);
        atomicAdd(&out[2 * c.y], gb.x);
        atomicAdd(&out[2 * c.y + 1], gb.y);
        atomicAdd(&out[2 * c.z], gc.x);
        atomicAdd(&out[2 * c.z + 1], gc.y);
        atomicAdd(&out[2 * c.w], gd.x);
        atomicAdd(&out[2 * c.w + 1], gd.y);
    }
    for (int e = (ne4 << 2) + tid; e < ne; e += stride) {
        float2 g = gp2[row[e]];
        atomicAdd(&out[2 * col[e]], g.x);
        atomicAdd(&out[2 * col[e] + 1], g.y);
    }
}

__global__ void k_final(const float* __restrict__ dis, const float* __restrict__ b2,
                        float* __restrict__ out, int n) {
    int i = blockIdx.x * blockDim.x + threadIdx.x;
    if (i >= n) return;
    float d = dis[i];
    float2* out2 = (float2*)out;
    float2 t = out2[i];
    out2[i] = make_float2(d * t.x + b2[0], d * t.y + b2[1]);
}

extern "C" void kernel_launch(void* const* d_in, const int* in_sizes, int n_in,
                              void* d_out, int out_size, void* d_ws, size_t ws_size,
                              hipStream_t stream) {
    const float* x = (const float*)d_in[0];
    const int* edge_index = (const int*)d_in[1];
    const float* W1 = (const float*)d_in[2];
    const float* b1 = (const float*)d_in[3];
    const float* W2 = (const float*)d_in[4];
    const float* b2 = (const float*)d_in[5];
    float* out = (float*)d_out;

    int n = in_sizes[0];           // N_NODES (x is [N,1])
    int ne = in_sizes[1] / 2;      // N_EDGES (edge_index is [2,E])
    const int* row = edge_index;       // edge_index[0]
    const int* col = edge_index + ne;  // edge_index[1]

    float* ws = (float*)d_ws;
    float* deg_dis = ws;           // [0, n)
    float* p = ws + n;             // [n, 2n)
    float* s = ws + 2 * (size_t)n; // [2n, 3n)
    float* gp = ws + 3 * (size_t)n;// [3n, 5n)

    int nodeBlocks = (n + TPB - 1) / TPB;
    int ne4 = ne >> 2;
    int edgeBlocks = (ne4 + TPB - 1) / TPB;
    if (edgeBlocks > EDGE_BLOCKS) edgeBlocks = EDGE_BLOCKS;
    if (edgeBlocks < 1) edgeBlocks = 1;

    k_init_deg<<<nodeBlocks, TPB, 0, stream>>>(deg_dis, n);
    k_deg<<<edgeBlocks, TPB, 0, stream>>>(col, deg_dis, ne);
    k_dis<<<nodeBlocks, TPB, 0, stream>>>(x, deg_dis, p, s, n);
    k_scatter1<<<edgeBlocks, TPB, 0, stream>>>(row, col, p, s, ne);
    k_node<<<nodeBlocks, TPB, 0, stream>>>(deg_dis, s, W1, b1, W2, b2, gp, out, n);
    k_scatter2<<<edgeBlocks, TPB, 0, stream>>>(row, col, gp, out, ne);
    k_final<<<nodeBlocks, TPB, 0, stream>>>(deg_dis, b2, out, n);
}

// Round 2
// 477.923 us; speedup vs baseline: 6.5229x; 6.5229x over previous
//
#include <hip/hip_runtime.h>

// GCN 2-layer, collapsed (x is [N,1] so layer 1 is rank-1):
//   out[c] = dis[c]*(sum_{r->c} gp[r] + gp[c]) + b2,   gp[r] = (relu(W1*a[r]+b1)@W2)*dis[r]
//   a[r]   = dis[r]*(sum_{r'->r} p[r'] + p[r]),        p[r'] = x[r']*dis[r'], dis=1/sqrt(deg+1)
//
// Strategy: NO global atomics (R1 showed 20.6G atomics/s fabric limit = 3.1ms).
// Two-level counting sort of edges into 512-node buckets, then per-bucket
// LDS aggregation. All heavy traffic is streaming; gathers hit L2/LLC-resident
// 2-4MB tables.

#define TPB 256
#define PART_BLOCKS 1024
#define BSHIFT 9
#define BNODES 512          // 1 << BSHIFT
#define KMAX 2048           // max buckets supported (n <= 1M)

// ---------------- fast path kernels ----------------

__global__ void k_count(const int* __restrict__ col, int ne, int ne4,
                        int* __restrict__ counts, int K) {
    __shared__ int cnt[KMAX];
    for (int i = threadIdx.x; i < K; i += blockDim.x) cnt[i] = 0;
    __syncthreads();
    int tid = blockIdx.x * blockDim.x + threadIdx.x;
    int stride = gridDim.x * blockDim.x;
    const int4* col4 = (const int4*)col;
    for (int e = tid; e < ne4; e += stride) {
        int4 c = col4[e];
        atomicAdd(&cnt[c.x >> BSHIFT], 1);
        atomicAdd(&cnt[c.y >> BSHIFT], 1);
        atomicAdd(&cnt[c.z >> BSHIFT], 1);
        atomicAdd(&cnt[c.w >> BSHIFT], 1);
    }
    for (int e = (ne4 << 2) + tid; e < ne; e += stride)
        atomicAdd(&cnt[col[e] >> BSHIFT], 1);
    __syncthreads();
    int B = gridDim.x;
    for (int k = threadIdx.x; k < K; k += blockDim.x)
        counts[(size_t)k * B + blockIdx.x] = cnt[k];
}

// one block per bucket: exclusive scan counts[k][0..B) in place, total -> btotal[k]
__global__ void k_scan_blocks(int* __restrict__ counts, int* __restrict__ btotal) {
    __shared__ int buf[PART_BLOCKS];
    __shared__ int csum[TPB + 1];
    int k = blockIdx.x;
    int* rowp = counts + (size_t)k * PART_BLOCKS;
    for (int i = threadIdx.x; i < PART_BLOCKS; i += TPB) buf[i] = rowp[i];
    __syncthreads();
    const int C = PART_BLOCKS / TPB;
    int base = threadIdx.x * C;
    int sum = 0;
#pragma unroll
    for (int j = 0; j < C; ++j) sum += buf[base + j];
    csum[threadIdx.x + 1] = sum;
    __syncthreads();
    if (threadIdx.x == 0) {
        csum[0] = 0;
        for (int t = 1; t <= TPB; ++t) csum[t] += csum[t - 1];
        btotal[k] = csum[TPB];
    }
    __syncthreads();
    int run = csum[threadIdx.x];
#pragma unroll
    for (int j = 0; j < C; ++j) { int t = buf[base + j]; buf[base + j] = run; run += t; }
    __syncthreads();
    for (int i = threadIdx.x; i < PART_BLOCKS; i += TPB) rowp[i] = buf[i];
}

// single block: exclusive scan of btotal[K] -> bbase[K], bbase[K] = ne
__global__ void k_scan_buckets(const int* __restrict__ btotal, int* __restrict__ bbase, int K) {
    __shared__ int buf[KMAX];
    __shared__ int csum[TPB + 1];
    for (int i = threadIdx.x; i < K; i += TPB) buf[i] = btotal[i];
    __syncthreads();
    int C = (K + TPB - 1) / TPB;
    int base = threadIdx.x * C;
    int sum = 0;
    for (int j = 0; j < C; ++j) { int idx = base + j; if (idx < K) sum += buf[idx]; }
    csum[threadIdx.x + 1] = sum;
    __syncthreads();
    if (threadIdx.x == 0) {
        csum[0] = 0;
        for (int t = 1; t <= TPB; ++t) csum[t] += csum[t - 1];
    }
    __syncthreads();
    int run = csum[threadIdx.x];
    for (int j = 0; j < C; ++j) {
        int idx = base + j;
        if (idx < K) { int t = buf[idx]; bbase[idx] = run; run += t; }
    }
    if (threadIdx.x == 0) bbase[K] = csum[TPB];
}

__global__ void k_partition(const int* __restrict__ row, const int* __restrict__ col,
                            int ne, int ne4,
                            const int* __restrict__ blockoff, const int* __restrict__ bbase,
                            int* __restrict__ packed, int K) {
    __shared__ int basepos[KMAX];
    int B = gridDim.x;
    for (int i = threadIdx.x; i < K; i += blockDim.x)
        basepos[i] = bbase[i] + blockoff[(size_t)i * B + blockIdx.x];
    __syncthreads();
    int tid = blockIdx.x * blockDim.x + threadIdx.x;
    int stride = gridDim.x * blockDim.x;
    const int4* row4 = (const int4*)row;
    const int4* col4 = (const int4*)col;
    for (int e = tid; e < ne4; e += stride) {
        int4 r = row4[e];
        int4 c = col4[e];
        int p0 = atomicAdd(&basepos[c.x >> BSHIFT], 1);
        packed[p0] = (r.x << BSHIFT) | (c.x & (BNODES - 1));
        int p1 = atomicAdd(&basepos[c.y >> BSHIFT], 1);
        packed[p1] = (r.y << BSHIFT) | (c.y & (BNODES - 1));
        int p2 = atomicAdd(&basepos[c.z >> BSHIFT], 1);
        packed[p2] = (r.z << BSHIFT) | (c.z & (BNODES - 1));
        int p3 = atomicAdd(&basepos[c.w >> BSHIFT], 1);
        packed[p3] = (r.w << BSHIFT) | (c.w & (BNODES - 1));
    }
    for (int e = (ne4 << 2) + tid; e < ne; e += stride) {
        int r = row[e], c = col[e];
        int p0 = atomicAdd(&basepos[c >> BSHIFT], 1);
        packed[p0] = (r << BSHIFT) | (c & (BNODES - 1));
    }
}

// one block per bucket: degree count in LDS -> dis = 1/sqrt(deg+1), p = x*dis
__global__ void k_dis_p(const float* __restrict__ x, const int* __restrict__ packed,
                        const int* __restrict__ bbase,
                        float* __restrict__ dis, float* __restrict__ p, int n) {
    __shared__ int cnt[BNODES];
    int k = blockIdx.x;
    int node0 = k << BSHIFT;
    int nn = min(BNODES, n - node0);
    for (int i = threadIdx.x; i < nn; i += blockDim.x) cnt[i] = 0;
    __syncthreads();
    int e0 = bbase[k], e1 = bbase[k + 1];
    for (int e = e0 + threadIdx.x; e < e1; e += blockDim.x)
        atomicAdd(&cnt[packed[e] & (BNODES - 1)], 1);
    __syncthreads();
    for (int i = threadIdx.x; i < nn; i += blockDim.x) {
        float d = (float)(cnt[i] + 1);  // +1 self-loop
        float ds = 1.0f / sqrtf(d);
        dis[node0 + i] = ds;
        p[node0 + i] = x[node0 + i] * ds;
    }
}

// one block per bucket: s = sum p[row]; fused MLP -> gp (float2)
__global__ void k_s_gp(const int* __restrict__ packed, const int* __restrict__ bbase,
                       const float* __restrict__ p, const float* __restrict__ dis,
                       const float* __restrict__ W1, const float* __restrict__ b1,
                       const float* __restrict__ W2,
                       float* __restrict__ gp, int n) {
    __shared__ float s[BNODES];
    int k = blockIdx.x;
    int node0 = k << BSHIFT;
    int nn = min(BNODES, n - node0);
    for (int i = threadIdx.x; i < nn; i += blockDim.x) s[i] = 0.0f;
    __syncthreads();
    int e0 = bbase[k], e1 = bbase[k + 1];
    for (int e = e0 + threadIdx.x; e < e1; e += blockDim.x) {
        int pk = packed[e];
        atomicAdd(&s[pk & (BNODES - 1)], p[pk >> BSHIFT]);
    }
    __syncthreads();
    float2* gp2 = (float2*)gp;
    for (int i = threadIdx.x; i < nn; i += blockDim.x) {
        int node = node0 + i;
        float d = dis[node];
        float a = d * (s[i] + p[node]);  // self-loop term
        float g0 = 0.0f, g1 = 0.0f;
#pragma unroll
        for (int q = 0; q < 16; ++q) {
            float h = fmaxf(W1[q] * a + b1[q], 0.0f);
            g0 += h * W2[2 * q];
            g1 += h * W2[2 * q + 1];
        }
        gp2[node] = make_float2(g0 * d, g1 * d);
    }
}

// one block per bucket: out = dis*(sum gp[row] + gp[self]) + b2
__global__ void k_out(const int* __restrict__ packed, const int* __restrict__ bbase,
                      const float* __restrict__ gp, const float* __restrict__ dis,
                      const float* __restrict__ b2, float* __restrict__ out, int n) {
    __shared__ float ox[BNODES];
    __shared__ float oy[BNODES];
    int k = blockIdx.x;
    int node0 = k << BSHIFT;
    int nn = min(BNODES, n - node0);
    for (int i = threadIdx.x; i < nn; i += blockDim.x) { ox[i] = 0.0f; oy[i] = 0.0f; }
    __syncthreads();
    int e0 = bbase[k], e1 = bbase[k + 1];
    const float2* gp2 = (const float2*)gp;
    for (int e = e0 + threadIdx.x; e < e1; e += blockDim.x) {
        int pk = packed[e];
        float2 g = gp2[pk >> BSHIFT];
        int c = pk & (BNODES - 1);
        atomicAdd(&ox[c], g.x);
        atomicAdd(&oy[c], g.y);
    }
    __syncthreads();
    float b20 = b2[0], b21 = b2[1];
    float2* out2 = (float2*)out;
    for (int i = threadIdx.x; i < nn; i += blockDim.x) {
        int node = node0 + i;
        float d = dis[node];
        float2 g = gp2[node];
        out2[node] = make_float2(d * (ox[i] + g.x) + b20, d * (oy[i] + g.y) + b21);
    }
}

// ---------------- fallback path (R1, global atomics) ----------------

__global__ void f_init_deg(float* __restrict__ deg, int n) {
    int i = blockIdx.x * blockDim.x + threadIdx.x;
    if (i < n) deg[i] = 1.0f;
}
__global__ void f_deg(const int* __restrict__ col, float* __restrict__ deg, int ne) {
    int tid = blockIdx.x * blockDim.x + threadIdx.x;
    int stride = gridDim.x * blockDim.x;
    for (int e = tid; e < ne; e += stride) atomicAdd(&deg[col[e]], 1.0f);
}
__global__ void f_dis(const float* __restrict__ x, float* __restrict__ deg_dis,
                      float* __restrict__ p, float* __restrict__ s, int n) {
    int i = blockIdx.x * blockDim.x + threadIdx.x;
    if (i >= n) return;
    float dis = 1.0f / sqrtf(deg_dis[i]);
    deg_dis[i] = dis;
    float pv = x[i] * dis;
    p[i] = pv;
    s[i] = pv;
}
__global__ void f_scatter1(const int* __restrict__ row, const int* __restrict__ col,
                           const float* __restrict__ p, float* __restrict__ s, int ne) {
    int tid = blockIdx.x * blockDim.x + threadIdx.x;
    int stride = gridDim.x * blockDim.x;
    for (int e = tid; e < ne; e += stride) atomicAdd(&s[col[e]], p[row[e]]);
}
__global__ void f_node(const float* __restrict__ dis, const float* __restrict__ s,
                       const float* __restrict__ W1, const float* __restrict__ b1,
                       const float* __restrict__ W2,
                       float* __restrict__ gp, float* __restrict__ out, int n) {
    int i = blockIdx.x * blockDim.x + threadIdx.x;
    if (i >= n) return;
    float d = dis[i];
    float a = d * s[i];
    float g0 = 0.0f, g1 = 0.0f;
#pragma unroll
    for (int q = 0; q < 16; ++q) {
        float h = fmaxf(W1[q] * a + b1[q], 0.0f);
        g0 += h * W2[2 * q];
        g1 += h * W2[2 * q + 1];
    }
    ((float2*)gp)[i] = make_float2(g0 * d, g1 * d);
    ((float2*)out)[i] = make_float2(g0 * d, g1 * d);
}
__global__ void f_scatter2(const int* __restrict__ row, const int* __restrict__ col,
                           const float* __restrict__ gp, float* __restrict__ out, int ne) {
    int tid = blockIdx.x * blockDim.x + threadIdx.x;
    int stride = gridDim.x * blockDim.x;
    const float2* gp2 = (const float2*)gp;
    for (int e = tid; e < ne; e += stride) {
        float2 g = gp2[row[e]];
        atomicAdd(&out[2 * col[e]], g.x);
        atomicAdd(&out[2 * col[e] + 1], g.y);
    }
}
__global__ void f_final(const float* __restrict__ dis, const float* __restrict__ b2,
                        float* __restrict__ out, int n) {
    int i = blockIdx.x * blockDim.x + threadIdx.x;
    if (i >= n) return;
    float d = dis[i];
    float2* out2 = (float2*)out;
    float2 t = out2[i];
    out2[i] = make_float2(d * t.x + b2[0], d * t.y + b2[1]);
}

// ---------------- launch ----------------

extern "C" void kernel_launch(void* const* d_in, const int* in_sizes, int n_in,
                              void* d_out, int out_size, void* d_ws, size_t ws_size,
                              hipStream_t stream) {
    const float* x = (const float*)d_in[0];
    const int* edge_index = (const int*)d_in[1];
    const float* W1 = (const float*)d_in[2];
    const float* b1 = (const float*)d_in[3];
    const float* W2 = (const float*)d_in[4];
    const float* b2 = (const float*)d_in[5];
    float* out = (float*)d_out;

    int n = in_sizes[0];
    int ne = in_sizes[1] / 2;
    const int* row = edge_index;
    const int* col = edge_index + ne;

    int K = (n + BNODES - 1) >> BSHIFT;

    // workspace carve-out (256B aligned)
    size_t off = 0;
    auto alloc = [&](size_t bytes) -> char* {
        char* ptr = (char*)d_ws + off;
        off += (bytes + 255) & ~(size_t)255;
        return ptr;
    };
    int* counts = (int*)alloc((size_t)K * PART_BLOCKS * sizeof(int));
    int* btotal = (int*)alloc((size_t)K * sizeof(int));
    int* bbase = (int*)alloc((size_t)(K + 1) * sizeof(int));
    int* packed = (int*)alloc((size_t)ne * sizeof(int));
    float* dis = (float*)alloc((size_t)n * sizeof(float));
    float* p = (float*)alloc((size_t)n * sizeof(float));
    float* gp = (float*)alloc((size_t)n * 2 * sizeof(float));

    bool fast = (off <= ws_size) && (K <= KMAX) && (n <= (KMAX << BSHIFT));

    int nodeBlocks = (n + TPB - 1) / TPB;
    // int4 path only if col pointer 16B-aligned (true when ne % 4 == 0, since row is aligned)
    int ne4 = ((ne & 3) == 0) ? (ne >> 2) : 0;

    if (fast) {
        k_count<<<PART_BLOCKS, TPB, 0, stream>>>(col, ne, ne4, counts, K);
        k_scan_blocks<<<K, TPB, 0, stream>>>(counts, btotal);
        k_scan_buckets<<<1, TPB, 0, stream>>>(btotal, bbase, K);
        k_partition<<<PART_BLOCKS, TPB, 0, stream>>>(row, col, ne, ne4, counts, bbase, packed, K);
        k_dis_p<<<K, TPB, 0, stream>>>(x, packed, bbase, dis, p, n);
        k_s_gp<<<K, TPB, 0, stream>>>(packed, bbase, p, dis, W1, b1, W2, gp, n);
        k_out<<<K, TPB, 0, stream>>>(packed, bbase, gp, dis, b2, out, n);
    } else {
        // fallback: global-atomic path (needs 5n floats)
        float* ws = (float*)d_ws;
        float* deg_dis = ws;
        float* pp = ws + n;
        float* ss = ws + 2 * (size_t)n;
        float* gpp = ws + 3 * (size_t)n;
        int edgeBlocks = 4096;
        f_init_deg<<<nodeBlocks, TPB, 0, stream>>>(deg_dis, n);
        f_deg<<<edgeBlocks, TPB, 0, stream>>>(col, deg_dis, ne);
        f_dis<<<nodeBlocks, TPB, 0, stream>>>(x, deg_dis, pp, ss, n);
        f_scatter1<<<edgeBlocks, TPB, 0, stream>>>(row, col, pp, ss, ne);
        f_node<<<nodeBlocks, TPB, 0, stream>>>(deg_dis, ss, W1, b1, W2, gpp, out, n);
        f_scatter2<<<edgeBlocks, TPB, 0, stream>>>(row, col, gpp, out, ne);
        f_final<<<nodeBlocks, TPB, 0, stream>>>(deg_dis, b2, out, n);
    }
}